// Round 1
// baseline (350.329 us; speedup 1.0000x reference)
//
#include <hip/hip_runtime.h>

#define HH 2048
#define WW 2048
#define CC 14
#define TILE 30
#define NT 69            // ceil(2048/30)
#define NB (NT*NT)       // 4761
#define PB 4768          // padded per-channel block-result stride

#define PINF __int_as_float(0x7f800000)
#define NINF __int_as_float(0xff800000)

// ---------------- DPP wave64 reduction (VALU pipe, no DS ops) ----------------
template<int CTRL>
__device__ __forceinline__ float dppf(float x) {
  return __int_as_float(__builtin_amdgcn_update_dpp(0, __float_as_int(x), CTRL, 0xF, 0xF, true));
}
template<int CTRL>
__device__ __forceinline__ int dppi(int x) {
  return __builtin_amdgcn_update_dpp(0, x, CTRL, 0xF, 0xF, true);
}

struct Red { float mn, sm, t0, t1; int ct; };

template<int CTRL>
__device__ __forceinline__ void red_step(Red& r) {
  float omn = dppf<CTRL>(r.mn);
  float osm = dppf<CTRL>(r.sm);
  float o0  = dppf<CTRL>(r.t0);
  float o1  = dppf<CTRL>(r.t1);
  int   oc  = dppi<CTRL>(r.ct);
  r.mn = fminf(r.mn, omn);
  r.sm += osm;
  r.ct += oc;
  float n1 = fmaxf(fminf(r.t0, o0), fmaxf(r.t1, o1));  // merged 2nd-of-top2
  r.t0 = fmaxf(r.t0, o0);
  r.t1 = n1;
}

// quad_perm xor1, xor2, row_half_mirror, row_mirror, row_bcast15, row_bcast31
// -> full-wave result valid in lane 63. bound_ctrl=0-fill only corrupts lanes
// outside the lane-15/31/47 -> lane-63 accumulation path.
__device__ __forceinline__ void wave_reduce(Red& r) {
  red_step<0xB1>(r);
  red_step<0x4E>(r);
  red_step<0x141>(r);
  red_step<0x140>(r);
  red_step<0x142>(r);
  red_step<0x143>(r);
}

__device__ __forceinline__ void merge2(float& a0, float& a1, float b0, float b1) {
  float n1 = fmaxf(fminf(a0, b0), fmaxf(a1, b1));
  a0 = fmaxf(a0, b0);
  a1 = n1;
}

// ws layout (buffer mode):
//   [0,128)                    double loss[14] (padded)
//   [128, +CC*PB*4)            float minb
//   then sumb(float), cntb(int), t0b(float), t1b(float), each CC*PB*4 bytes
// ws layout (atomic fallback mode):
//   [0,128) double wsum[14]; [128) uint wmin[14]; [192) int wcnt[14];
//   [256) uint s0[14]; [320) uint s1[14]
__global__ __launch_bounds__(256, 2)
void k_main(const float* __restrict__ X, char* __restrict__ ws, int mode) {
  const int tid = threadIdx.x;
  const int bx = blockIdx.x, by = blockIdx.y;
  const int blk = by * NT + bx;
  const int rr = tid >> 3, c8 = tid & 7, c0 = c8 << 2;
  const int gr = by * TILE - 1 + rr;
  const int gc0 = bx * TILE - 1 + c0;
  const int lane = tid & 63, wv = tid >> 6;

  __shared__ float4 hplane[32][8];
  __shared__ float redmn[CC][4], redsm[CC][4], redt0[CC][4], redt1[CC][4];
  __shared__ int   redct[CC][4];

  // ---- load 32x32 region, all 14 channels, into registers ----
  float xv[CC][4];
  const bool rowok = ((unsigned)gr < (unsigned)HH);
  const int grc = rowok ? gr : 0;
  bool ok[4];
#pragma unroll
  for (int k = 0; k < 4; ++k) ok[k] = rowok && ((unsigned)(gc0 + k) < (unsigned)WW);
  const float* base = X + (size_t)grc * WW;
#pragma unroll
  for (int c = 0; c < CC; ++c) {
#pragma unroll
    for (int k = 0; k < 4; ++k) {
      int gck = gc0 + k;
      int gcc = ((unsigned)gck < (unsigned)WW) ? gck : 0;
      float v = base[(size_t)c * (size_t)(HH * WW) + gcc];
      xv[c][k] = ok[k] ? v : 0.0f;
    }
  }

  // ---- softmax over channels, per pixel (max-subtracted, like jax) ----
#pragma unroll
  for (int k = 0; k < 4; ++k) {
    float m = xv[0][k];
#pragma unroll
    for (int c = 1; c < CC; ++c) m = fmaxf(m, xv[c][k]);
    float s = 0.f;
#pragma unroll
    for (int c = 0; c < CC; ++c) { float e = __expf(xv[c][k] - m); s += e; xv[c][k] = e; }
    float ri = 1.0f / s;
#pragma unroll
    for (int c = 0; c < CC; ++c) xv[c][k] = ok[k] ? xv[c][k] * ri : NINF;  // OOB = -inf pad
  }

  // ---- interior mask (channel-independent): each image pixel in exactly one tile interior
  bool inter[4];
  const bool rin = (rr >= 1) && (rr <= 30) && (gr < HH);
#pragma unroll
  for (int k = 0; k < 4; ++k) {
    int cc = c0 + k;
    inter[k] = rin && (cc >= 1) && (cc <= 30) && ((gc0 + k) < WW);
  }

  const int ru = (rr >= 1) ? rr - 1 : 0;
  const int rd = (rr <= 30) ? rr + 1 : 31;

#pragma unroll
  for (int c = 0; c < CC; ++c) {
    const float p0 = xv[c][0], p1 = xv[c][1], p2 = xv[c][2], p3 = xv[c][3];
    float pm1 = __shfl_up(p3, 1);   if (c8 == 0) pm1 = NINF;  // col-1 (never feeds interior)
    float pp4 = __shfl_down(p0, 1); if (c8 == 7) pp4 = NINF;  // col+4
    const float hf0 = fmaxf(fmaxf(pm1, p0), p1);
    const float hf1 = fmaxf(fmaxf(p0, p1), p2);
    const float hf2 = fmaxf(fmaxf(p1, p2), p3);
    const float hf3 = fmaxf(fmaxf(p2, p3), pp4);
    const float hl0 = fmaxf(pm1, p1);
    const float hl1 = fmaxf(p0, p2);
    const float hl2 = fmaxf(p1, p3);
    const float hl3 = fmaxf(p2, pp4);
    __syncthreads();                       // previous channel's hplane reads done
    hplane[rr][c8] = make_float4(hf0, hf1, hf2, hf3);
    __syncthreads();
    const float4 up = hplane[ru][c8];
    const float4 dn = hplane[rd][c8];

    Red r; r.mn = PINF; r.sm = 0.f; r.ct = 0; r.t0 = NINF; r.t1 = NINF;
    {
      const float nb = fmaxf(fmaxf(up.x, dn.x), hl0);
      const bool im = inter[0] && (p0 > nb);
      r.mn = inter[0] ? fminf(r.mn, p0) : r.mn;
      if (im) { r.sm += p0; r.ct++; r.t1 = fmaxf(r.t1, fminf(r.t0, p0)); r.t0 = fmaxf(r.t0, p0); }
    }
    {
      const float nb = fmaxf(fmaxf(up.y, dn.y), hl1);
      const bool im = inter[1] && (p1 > nb);
      r.mn = inter[1] ? fminf(r.mn, p1) : r.mn;
      if (im) { r.sm += p1; r.ct++; r.t1 = fmaxf(r.t1, fminf(r.t0, p1)); r.t0 = fmaxf(r.t0, p1); }
    }
    {
      const float nb = fmaxf(fmaxf(up.z, dn.z), hl2);
      const bool im = inter[2] && (p2 > nb);
      r.mn = inter[2] ? fminf(r.mn, p2) : r.mn;
      if (im) { r.sm += p2; r.ct++; r.t1 = fmaxf(r.t1, fminf(r.t0, p2)); r.t0 = fmaxf(r.t0, p2); }
    }
    {
      const float nb = fmaxf(fmaxf(up.w, dn.w), hl3);
      const bool im = inter[3] && (p3 > nb);
      r.mn = inter[3] ? fminf(r.mn, p3) : r.mn;
      if (im) { r.sm += p3; r.ct++; r.t1 = fmaxf(r.t1, fminf(r.t0, p3)); r.t0 = fmaxf(r.t0, p3); }
    }

    wave_reduce(r);
    if (lane == 63) {
      redmn[c][wv] = r.mn; redsm[c][wv] = r.sm; redct[c][wv] = r.ct;
      redt0[c][wv] = r.t0; redt1[c][wv] = r.t1;
    }
  }

  __syncthreads();
  if (tid < CC) {
    const int c = tid;
    float mn = fminf(fminf(redmn[c][0], redmn[c][1]), fminf(redmn[c][2], redmn[c][3]));
    float sm = redsm[c][0] + redsm[c][1] + redsm[c][2] + redsm[c][3];
    int   ct = redct[c][0] + redct[c][1] + redct[c][2] + redct[c][3];
    float a0 = redt0[c][0], a1 = redt1[c][0];
    merge2(a0, a1, redt0[c][1], redt1[c][1]);
    merge2(a0, a1, redt0[c][2], redt1[c][2]);
    merge2(a0, a1, redt0[c][3], redt1[c][3]);

    if (mode == 0) {
      float* minb = (float*)(ws + 128);
      float* sumb = minb + CC * PB;
      int*   cntb = (int*)(sumb + CC * PB);
      float* t0b  = (float*)(cntb + CC * PB);
      float* t1b  = t0b + CC * PB;
      const int o = c * PB + blk;
      minb[o] = mn; sumb[o] = sm; cntb[o] = ct; t0b[o] = a0; t1b[o] = a1;
    } else {
      double*   wsum = (double*)ws;
      unsigned* wmin = (unsigned*)(ws + 128);
      int*      wcnt = (int*)(ws + 192);
      unsigned* s0   = (unsigned*)(ws + 256);
      unsigned* s1   = (unsigned*)(ws + 320);
      atomicMin(&wmin[c], __float_as_uint(mn));   // probs >= 0: uint order == float order
      atomicAdd(&wsum[c], (double)sm);
      atomicAdd(&wcnt[c], ct);
      if (a0 != NINF) {
        unsigned b = __float_as_uint(a0);
        unsigned o = atomicMax(&s0[c], b);
        unsigned w2 = o < b ? o : b;
        if (w2) atomicMax(&s1[c], w2);
      }
      if (a1 != NINF) {
        unsigned b = __float_as_uint(a1);
        unsigned o = atomicMax(&s0[c], b);
        unsigned w2 = o < b ? o : b;
        if (w2) atomicMax(&s1[c], w2);
      }
    }
  }
}

// -------- buffer-mode reduction: one block per channel --------
__global__ void k_reduce(char* __restrict__ ws) {
  const int c = blockIdx.x, tid = threadIdx.x;
  double* lossb = (double*)ws;
  const float* minb = (const float*)(ws + 128);
  const float* sumb = minb + CC * PB;
  const int*   cntb = (const int*)(sumb + CC * PB);
  const float* t0b  = (const float*)(cntb + CC * PB);
  const float* t1b  = t0b + CC * PB;

  float mn = PINF; double sm = 0.0; int ct = 0; float t0 = NINF, t1 = NINF;
  const int o = c * PB;
  for (int i = tid; i < NB; i += 256) {
    mn = fminf(mn, minb[o + i]);
    sm += (double)sumb[o + i];
    ct += cntb[o + i];
    float b0 = t0b[o + i], b1 = t1b[o + i];
    t1 = fmaxf(t1, fminf(t0, b0)); t0 = fmaxf(t0, b0);
    t1 = fmaxf(t1, fminf(t0, b1)); t0 = fmaxf(t0, b1);
  }
  for (int m = 1; m < 64; m <<= 1) {
    float omn = __shfl_xor(mn, m);
    double osm = __shfl_xor(sm, m);
    int oc = __shfl_xor(ct, m);
    float o0 = __shfl_xor(t0, m), o1 = __shfl_xor(t1, m);
    mn = fminf(mn, omn); sm += osm; ct += oc;
    float n1 = fmaxf(fminf(t0, o0), fmaxf(t1, o1));
    t0 = fmaxf(t0, o0); t1 = n1;
  }
  __shared__ float smn[4], st0[4], st1[4];
  __shared__ double ssm[4];
  __shared__ int sct[4];
  const int lane = tid & 63, wv = tid >> 6;
  if (lane == 0) { smn[wv] = mn; ssm[wv] = sm; sct[wv] = ct; st0[wv] = t0; st1[wv] = t1; }
  __syncthreads();
  if (tid == 0) {
    mn = smn[0]; sm = ssm[0]; ct = sct[0]; t0 = st0[0]; t1 = st1[0];
    for (int w = 1; w < 4; ++w) {
      mn = fminf(mn, smn[w]); sm += ssm[w]; ct += sct[w];
      float n1 = fmaxf(fminf(t0, st0[w]), fmaxf(t1, st1[w]));
      t0 = fmaxf(t0, st0[w]); t1 = n1;
    }
    double minv = (double)mn;
    double total = sm - (double)ct * minv;
    const int kt = (c < 7) ? 1 : 2;
    double target = 0.0, hinge = 0.0;
    if (t0 != NINF) { double v = (double)t0 - minv; target += v; hinge += fmax(0.0, 1.0 - v); }
    if (kt == 2 && t1 != NINF) { double v = (double)t1 - minv; target += v; hinge += fmax(0.0, 1.0 - v); }
    lossb[c] = (total - target) + hinge;
  }
}

__global__ void k_final(const char* __restrict__ ws, float* __restrict__ out) {
  if (threadIdx.x == 0) {
    const double* lossb = (const double*)ws;
    double a = 0.0;
    for (int c = 0; c < CC; ++c) a += lossb[c];
    out[0] = (float)(a / (double)CC);
  }
}

// -------- atomic fallback (only if ws is tiny) --------
__global__ void k_init_atomic(char* __restrict__ ws) {
  const int i = threadIdx.x;
  if (i < CC) {
    ((double*)ws)[i] = 0.0;
    ((unsigned*)(ws + 128))[i] = 0x7f800000u;
    ((int*)(ws + 192))[i] = 0;
    ((unsigned*)(ws + 256))[i] = 0u;
    ((unsigned*)(ws + 320))[i] = 0u;
  }
}

__global__ void k_final_atomic(const char* __restrict__ ws, float* __restrict__ out) {
  if (threadIdx.x == 0) {
    const double*   wsum = (const double*)ws;
    const unsigned* wmin = (const unsigned*)(ws + 128);
    const int*      wcnt = (const int*)(ws + 192);
    const unsigned* s0   = (const unsigned*)(ws + 256);
    const unsigned* s1   = (const unsigned*)(ws + 320);
    double a = 0.0;
    for (int c = 0; c < CC; ++c) {
      double minv = (double)__uint_as_float(wmin[c]);
      double total = wsum[c] - (double)wcnt[c] * minv;
      const int kt = (c < 7) ? 1 : 2;
      double target = 0.0, hinge = 0.0;
      if (s0[c]) { double v = (double)__uint_as_float(s0[c]) - minv; target += v; hinge += fmax(0.0, 1.0 - v); }
      if (kt == 2 && s1[c]) { double v = (double)__uint_as_float(s1[c]) - minv; target += v; hinge += fmax(0.0, 1.0 - v); }
      a += (total - target) + hinge;
    }
    out[0] = (float)(a / (double)CC);
  }
}

extern "C" void kernel_launch(void* const* d_in, const int* in_sizes, int n_in,
                              void* d_out, int out_size, void* d_ws, size_t ws_size,
                              hipStream_t stream) {
  const float* X = (const float*)d_in[0];   // [1,14,2048,2048] f32 logits; d_in[1] (target) unused by the loss
  float* out = (float*)d_out;
  char* ws = (char*)d_ws;
  const size_t needBuf = 128 + (size_t)5 * CC * PB * 4;   // ~1.34 MB
  dim3 grid(NT, NT);
  if (ws_size >= needBuf) {
    k_main<<<grid, 256, 0, stream>>>(X, ws, 0);
    k_reduce<<<CC, 256, 0, stream>>>(ws);
    k_final<<<1, 64, 0, stream>>>(ws, out);
  } else {
    k_init_atomic<<<1, 64, 0, stream>>>(ws);
    k_main<<<grid, 256, 0, stream>>>(X, ws, 1);
    k_final_atomic<<<1, 64, 0, stream>>>(ws, out);
  }
}

// Round 5
// 347.290 us; speedup vs baseline: 1.0088x; 1.0088x over previous
//
#include <hip/hip_runtime.h>

#define HH 2048
#define WW 2048
#define HW (HH*WW)
#define CC 14
#define TILE 30
#define NT 69            // ceil(2048/30)
#define NB (NT*NT)       // 4761
#define PB 4768          // padded per-channel block-result stride

#define PINF __int_as_float(0x7f800000)
#define NINF __int_as_float(0xff800000)

typedef float f4 __attribute__((ext_vector_type(4)));

// Unaligned (4B-aligned) float4 load: memcpy -> load <4 x float>, align 4 ->
// global_load_dwordx4 (gfx9 global loads require dword alignment only).
__device__ __forceinline__ f4 load_f4u(const float* p) {
  f4 v;
  __builtin_memcpy(&v, p, 16);
  return v;
}

// ---------------- DPP helpers (VALU pipe, no DS ops) ----------------
template<int CTRL>
__device__ __forceinline__ float dppf(float x) {
  return __int_as_float(__builtin_amdgcn_update_dpp(0, __float_as_int(x), CTRL, 0xF, 0xF, true));
}
template<int CTRL>
__device__ __forceinline__ int dppi(int x) {
  return __builtin_amdgcn_update_dpp(0, x, CTRL, 0xF, 0xF, true);
}
// wave_shr:1 = 0x138 : Dst[l] = Src[l-1]  (left neighbor's value)
// wave_shl:1 = 0x130 : Dst[l] = Src[l+1]  (right neighbor's value)

struct Red { float mn, sm, t0, t1; int ct; };

template<int CTRL>
__device__ __forceinline__ void red_step(Red& r) {
  float omn = dppf<CTRL>(r.mn);
  float osm = dppf<CTRL>(r.sm);
  float o0  = dppf<CTRL>(r.t0);
  float o1  = dppf<CTRL>(r.t1);
  int   oc  = dppi<CTRL>(r.ct);
  r.mn = fminf(r.mn, omn);
  r.sm += osm;
  r.ct += oc;
  float n1 = fmaxf(fminf(r.t0, o0), fmaxf(r.t1, o1));  // merged 2nd-of-top2
  r.t0 = fmaxf(r.t0, o0);
  r.t1 = n1;
}

// 4-step reduce: xor1, xor2, row_half_mirror, row_mirror -> every lane holds
// its 16-lane group's reduction (no OOB lanes at any step).
__device__ __forceinline__ void wave_reduce16(Red& r) {
  red_step<0xB1>(r);
  red_step<0x4E>(r);
  red_step<0x141>(r);
  red_step<0x140>(r);
}

__device__ __forceinline__ void merge2(float& a0, float& a1, float b0, float b1) {
  float n1 = fmaxf(fminf(a0, b0), fmaxf(a1, b1));
  a0 = fmaxf(a0, b0);
  a1 = n1;
}

// ws layout (buffer mode):
//   [0,128)                    double loss[14] (padded)
//   [128, +CC*PB*4)            float minb
//   then sumb(float), cntb(int), t0b(float), t1b(float), each CC*PB*4 bytes
// ws layout (atomic fallback mode):
//   [0,128) double wsum[14]; [128) uint wmin[14]; [192) int wcnt[14];
//   [256) uint s0[14]; [320) uint s1[14]
__global__ __launch_bounds__(256, 4)
void k_main(const float* __restrict__ X, char* __restrict__ ws, int mode) {
  const int tid = threadIdx.x;
  const int bx = blockIdx.x, by = blockIdx.y;
  const int blk = by * NT + bx;
  const int rr = tid >> 3, c8 = tid & 7, c0 = c8 << 2;
  const int gr = by * TILE - 1 + rr;
  const int gc0 = bx * TILE - 1 + c0;
  const int lane = tid & 63, wv = tid >> 6;

  __shared__ f4 hplane[7][32][8];                       // 28.7 KB, one 7-channel group at a time
  __shared__ float redmn[CC][16], redsm[CC][16], redt0[CC][16], redt1[CC][16];
  __shared__ int   redct[CC][16];

  // ---- load 32x32 region, all 14 channels, into registers ----
  float xv[CC][4];
  bool ok[4];
  const bool fast = (bx >= 1) && (bx <= 67) && (by >= 1) && (by <= 67);
  if (fast) {
    ok[0] = ok[1] = ok[2] = ok[3] = true;
    const float* base = X + (size_t)gr * WW + gc0;
#pragma unroll
    for (int c = 0; c < CC; ++c) {
      f4 v = load_f4u(base + (size_t)c * (size_t)HW);
      xv[c][0] = v.x; xv[c][1] = v.y; xv[c][2] = v.z; xv[c][3] = v.w;
    }
  } else {
    const bool rowok = ((unsigned)gr < (unsigned)HH);
    const int grc = rowok ? gr : 0;
#pragma unroll
    for (int k = 0; k < 4; ++k) ok[k] = rowok && ((unsigned)(gc0 + k) < (unsigned)WW);
    const float* base = X + (size_t)grc * WW;
#pragma unroll
    for (int c = 0; c < CC; ++c) {
#pragma unroll
      for (int k = 0; k < 4; ++k) {
        int gck = gc0 + k;
        int gcc = ((unsigned)gck < (unsigned)WW) ? gck : 0;
        xv[c][k] = base[(size_t)c * (size_t)HW + gcc];
      }
    }
  }

  // ---- softmax over channels, per pixel (max-subtracted, like jax) ----
#pragma unroll
  for (int k = 0; k < 4; ++k) {
    float m = xv[0][k];
#pragma unroll
    for (int c = 1; c < CC; ++c) m = fmaxf(m, xv[c][k]);
    float s = 0.f;
#pragma unroll
    for (int c = 0; c < CC; ++c) { float e = __expf(xv[c][k] - m); s += e; xv[c][k] = e; }
    float ri = 1.0f / s;
#pragma unroll
    for (int c = 0; c < CC; ++c) xv[c][k] = ok[k] ? xv[c][k] * ri : NINF;  // OOB = -inf pad
  }

  // ---- interior mask (channel-independent): each image pixel in exactly one tile interior
  bool inter[4];
  const bool rin = (rr >= 1) && (rr <= 30) && (gr < HH);
#pragma unroll
  for (int k = 0; k < 4; ++k) {
    int cc = c0 + k;
    inter[k] = rin && (cc >= 1) && (cc <= 30) && ((gc0 + k) < WW);
  }

  const int ru = (rr >= 1) ? rr - 1 : 0;
  const int rd = (rr <= 30) ? rr + 1 : 31;

  // ---- two channel groups of 7: write all hf planes, 1 barrier, read+reduce, 1 barrier
#pragma unroll
  for (int g = 0; g < 2; ++g) {
    const int cbase = g * 7;
#pragma unroll
    for (int i = 0; i < 7; ++i) {
      const int c = cbase + i;
      const float p0 = xv[c][0], p1 = xv[c][1], p2 = xv[c][2], p3 = xv[c][3];
      float pm1 = dppf<0x138>(p3); if (c8 == 0) pm1 = NINF;  // col-1 (never feeds interior)
      float pp4 = dppf<0x130>(p0); if (c8 == 7) pp4 = NINF;  // col+4
      f4 hf;
      hf.x = fmaxf(fmaxf(pm1, p0), p1);
      hf.y = fmaxf(fmaxf(p0, p1), p2);
      hf.z = fmaxf(fmaxf(p1, p2), p3);
      hf.w = fmaxf(fmaxf(p2, p3), pp4);
      hplane[i][rr][c8] = hf;
    }
    __syncthreads();
#pragma unroll
    for (int i = 0; i < 7; ++i) {
      const int c = cbase + i;
      const f4 up = hplane[i][ru][c8];
      const f4 dn = hplane[i][rd][c8];
      const float p0 = xv[c][0], p1 = xv[c][1], p2 = xv[c][2], p3 = xv[c][3];
      float pm1 = dppf<0x138>(p3); if (c8 == 0) pm1 = NINF;
      float pp4 = dppf<0x130>(p0); if (c8 == 7) pp4 = NINF;
      const float hl0 = fmaxf(pm1, p1);
      const float hl1 = fmaxf(p0, p2);
      const float hl2 = fmaxf(p1, p3);
      const float hl3 = fmaxf(p2, pp4);

      Red r; r.mn = PINF; r.sm = 0.f; r.ct = 0; r.t0 = NINF; r.t1 = NINF;
      {
        const float nb = fmaxf(fmaxf(up.x, dn.x), hl0);
        const bool im = inter[0] && (p0 > nb);
        r.mn = inter[0] ? fminf(r.mn, p0) : r.mn;
        if (im) { r.sm += p0; r.ct++; r.t1 = fmaxf(r.t1, fminf(r.t0, p0)); r.t0 = fmaxf(r.t0, p0); }
      }
      {
        const float nb = fmaxf(fmaxf(up.y, dn.y), hl1);
        const bool im = inter[1] && (p1 > nb);
        r.mn = inter[1] ? fminf(r.mn, p1) : r.mn;
        if (im) { r.sm += p1; r.ct++; r.t1 = fmaxf(r.t1, fminf(r.t0, p1)); r.t0 = fmaxf(r.t0, p1); }
      }
      {
        const float nb = fmaxf(fmaxf(up.z, dn.z), hl2);
        const bool im = inter[2] && (p2 > nb);
        r.mn = inter[2] ? fminf(r.mn, p2) : r.mn;
        if (im) { r.sm += p2; r.ct++; r.t1 = fmaxf(r.t1, fminf(r.t0, p2)); r.t0 = fmaxf(r.t0, p2); }
      }
      {
        const float nb = fmaxf(fmaxf(up.w, dn.w), hl3);
        const bool im = inter[3] && (p3 > nb);
        r.mn = inter[3] ? fminf(r.mn, p3) : r.mn;
        if (im) { r.sm += p3; r.ct++; r.t1 = fmaxf(r.t1, fminf(r.t0, p3)); r.t0 = fmaxf(r.t0, p3); }
      }

      wave_reduce16(r);
      if ((lane & 15) == 0) {
        const int s = (wv << 2) | (lane >> 4);
        redmn[c][s] = r.mn; redsm[c][s] = r.sm; redct[c][s] = r.ct;
        redt0[c][s] = r.t0; redt1[c][s] = r.t1;
      }
    }
    __syncthreads();
  }

  if (tid < CC) {
    const int c = tid;
    float mn = PINF, sm = 0.f, a0 = NINF, a1 = NINF;
    int ct = 0;
#pragma unroll
    for (int s = 0; s < 16; ++s) {
      mn = fminf(mn, redmn[c][s]);
      sm += redsm[c][s];
      ct += redct[c][s];
      merge2(a0, a1, redt0[c][s], redt1[c][s]);
    }

    if (mode == 0) {
      float* minb = (float*)(ws + 128);
      float* sumb = minb + CC * PB;
      int*   cntb = (int*)(sumb + CC * PB);
      float* t0b  = (float*)(cntb + CC * PB);
      float* t1b  = t0b + CC * PB;
      const int o = c * PB + blk;
      minb[o] = mn; sumb[o] = sm; cntb[o] = ct; t0b[o] = a0; t1b[o] = a1;
    } else {
      double*   wsum = (double*)ws;
      unsigned* wmin = (unsigned*)(ws + 128);
      int*      wcnt = (int*)(ws + 192);
      unsigned* s0   = (unsigned*)(ws + 256);
      unsigned* s1   = (unsigned*)(ws + 320);
      atomicMin(&wmin[c], __float_as_uint(mn));   // probs >= 0: uint order == float order
      atomicAdd(&wsum[c], (double)sm);
      atomicAdd(&wcnt[c], ct);
      if (a0 != NINF) {
        unsigned b = __float_as_uint(a0);
        unsigned o = atomicMax(&s0[c], b);
        unsigned w2 = o < b ? o : b;
        if (w2) atomicMax(&s1[c], w2);
      }
      if (a1 != NINF) {
        unsigned b = __float_as_uint(a1);
        unsigned o = atomicMax(&s0[c], b);
        unsigned w2 = o < b ? o : b;
        if (w2) atomicMax(&s1[c], w2);
      }
    }
  }
}

// -------- buffer-mode reduction: one block per channel --------
__global__ void k_reduce(char* __restrict__ ws) {
  const int c = blockIdx.x, tid = threadIdx.x;
  double* lossb = (double*)ws;
  const float* minb = (const float*)(ws + 128);
  const float* sumb = minb + CC * PB;
  const int*   cntb = (const int*)(sumb + CC * PB);
  const float* t0b  = (const float*)(cntb + CC * PB);
  const float* t1b  = t0b + CC * PB;

  float mn = PINF; double sm = 0.0; int ct = 0; float t0 = NINF, t1 = NINF;
  const int o = c * PB;
  for (int i = tid; i < NB; i += 256) {
    mn = fminf(mn, minb[o + i]);
    sm += (double)sumb[o + i];
    ct += cntb[o + i];
    float b0 = t0b[o + i], b1 = t1b[o + i];
    t1 = fmaxf(t1, fminf(t0, b0)); t0 = fmaxf(t0, b0);
    t1 = fmaxf(t1, fminf(t0, b1)); t0 = fmaxf(t0, b1);
  }
  for (int m = 1; m < 64; m <<= 1) {
    float omn = __shfl_xor(mn, m);
    double osm = __shfl_xor(sm, m);
    int oc = __shfl_xor(ct, m);
    float o0 = __shfl_xor(t0, m), o1 = __shfl_xor(t1, m);
    mn = fminf(mn, omn); sm += osm; ct += oc;
    float n1 = fmaxf(fminf(t0, o0), fmaxf(t1, o1));
    t0 = fmaxf(t0, o0); t1 = n1;
  }
  __shared__ float smn[4], st0[4], st1[4];
  __shared__ double ssm[4];
  __shared__ int sct[4];
  const int lane = tid & 63, wv = tid >> 6;
  if (lane == 0) { smn[wv] = mn; ssm[wv] = sm; sct[wv] = ct; st0[wv] = t0; st1[wv] = t1; }
  __syncthreads();
  if (tid == 0) {
    mn = smn[0]; sm = ssm[0]; ct = sct[0]; t0 = st0[0]; t1 = st1[0];
    for (int w = 1; w < 4; ++w) {
      mn = fminf(mn, smn[w]); sm += ssm[w]; ct += sct[w];
      float n1 = fmaxf(fminf(t0, st0[w]), fmaxf(t1, st1[w]));
      t0 = fmaxf(t0, st0[w]); t1 = n1;
    }
    double minv = (double)mn;
    double total = sm - (double)ct * minv;
    const int kt = (c < 7) ? 1 : 2;
    double target = 0.0, hinge = 0.0;
    if (t0 != NINF) { double v = (double)t0 - minv; target += v; hinge += fmax(0.0, 1.0 - v); }
    if (kt == 2 && t1 != NINF) { double v = (double)t1 - minv; target += v; hinge += fmax(0.0, 1.0 - v); }
    lossb[c] = (total - target) + hinge;
  }
}

__global__ void k_final(const char* __restrict__ ws, float* __restrict__ out) {
  if (threadIdx.x == 0) {
    const double* lossb = (const double*)ws;
    double a = 0.0;
    for (int c = 0; c < CC; ++c) a += lossb[c];
    out[0] = (float)(a / (double)CC);
  }
}

// -------- atomic fallback (only if ws is tiny) --------
__global__ void k_init_atomic(char* __restrict__ ws) {
  const int i = threadIdx.x;
  if (i < CC) {
    ((double*)ws)[i] = 0.0;
    ((unsigned*)(ws + 128))[i] = 0x7f800000u;
    ((int*)(ws + 192))[i] = 0;
    ((unsigned*)(ws + 256))[i] = 0u;
    ((unsigned*)(ws + 320))[i] = 0u;
  }
}

__global__ void k_final_atomic(const char* __restrict__ ws, float* __restrict__ out) {
  if (threadIdx.x == 0) {
    const double*   wsum = (const double*)ws;
    const unsigned* wmin = (const unsigned*)(ws + 128);
    const int*      wcnt = (const int*)(ws + 192);
    const unsigned* s0   = (const unsigned*)(ws + 256);
    const unsigned* s1   = (const unsigned*)(ws + 320);
    double a = 0.0;
    for (int c = 0; c < CC; ++c) {
      double minv = (double)__uint_as_float(wmin[c]);
      double total = wsum[c] - (double)wcnt[c] * minv;
      const int kt = (c < 7) ? 1 : 2;
      double target = 0.0, hinge = 0.0;
      if (s0[c]) { double v = (double)__uint_as_float(s0[c]) - minv; target += v; hinge += fmax(0.0, 1.0 - v); }
      if (kt == 2 && s1[c]) { double v = (double)__uint_as_float(s1[c]) - minv; target += v; hinge += fmax(0.0, 1.0 - v); }
      a += (total - target) + hinge;
    }
    out[0] = (float)(a / (double)CC);
  }
}

extern "C" void kernel_launch(void* const* d_in, const int* in_sizes, int n_in,
                              void* d_out, int out_size, void* d_ws, size_t ws_size,
                              hipStream_t stream) {
  const float* X = (const float*)d_in[0];   // [1,14,2048,2048] f32 logits; d_in[1] (target) unused by the loss
  float* out = (float*)d_out;
  char* ws = (char*)d_ws;
  const size_t needBuf = 128 + (size_t)5 * CC * PB * 4;   // ~1.34 MB
  dim3 grid(NT, NT);
  if (ws_size >= needBuf) {
    k_main<<<grid, 256, 0, stream>>>(X, ws, 0);
    k_reduce<<<CC, 256, 0, stream>>>(ws);
    k_final<<<1, 64, 0, stream>>>(ws, out);
  } else {
    k_init_atomic<<<1, 64, 0, stream>>>(ws);
    k_main<<<grid, 256, 0, stream>>>(X, ws, 1);
    k_final_atomic<<<1, 64, 0, stream>>>(ws, out);
  }
}